// Round 2
// baseline (652.034 us; speedup 1.0000x reference)
//
#include <hip/hip_runtime.h>
#include <math.h>

typedef _Float16 f16x8 __attribute__((ext_vector_type(8)));
typedef _Float16 f16x2 __attribute__((ext_vector_type(2)));
typedef float    f32x4 __attribute__((ext_vector_type(4)));

// Fixed ECG graph: neighbor bitmasks and degrees (a_eff = adj + 2I, deg = rowsum).
// conns: (0,1),(0,2),(1,2),(0,3),(1,3),(2,3),(0,4),(1,4),(1,5),(2,5),(6,7),(7,8),(8,9),(9,10),(10,11)
namespace {
constexpr unsigned kMask[12] = {0x01Eu,0x03Du,0x02Bu,0x007u,0x003u,0x006u,
                                0x080u,0x140u,0x280u,0x500u,0xA00u,0x400u};
constexpr int kDeg[12] = {6,7,6,5,4,4,3,4,4,4,4,3};
}

// One GCN layer: out = act( A_norm @ (in @ W) + b ), fused as (A@in)@W with the
// 12x12 mix applied during LDS staging. M-tile 96 rows (8 batch groups of 12),
// full-N per block (x fetched once), 512 threads = 8 waves, wave-tile 48 x N/4.
template<int K, int N, bool IN_F16, bool RELU, bool POOL>
__global__ __launch_bounds__(512)
void gcn_layer(const void* __restrict__ inp,
               const _Float16* __restrict__ wt,   // W^T, N x K row-major fp16
               const float* __restrict__ bias,
               void* __restrict__ outp)
{
    constexpr int NT  = N / 64;            // MFMA n-tiles per wave (4 or 2)
    constexpr int AST = 72;                // LDS row stride in halves (64 + 8 pad)
    constexpr int ABYTES = 96 * AST * 2;
    constexpr int WBYTES = N * AST * 2;
    constexpr int STAGE_BYTES = ABYTES + WBYTES;
    constexpr int POOL_BYTES  = 96 * 129 * 4;
    constexpr int SMEM = (POOL && POOL_BYTES > STAGE_BYTES) ? POOL_BYTES : STAGE_BYTES;

    __shared__ __align__(16) char smem[SMEM];
    _Float16* Abuf = (_Float16*)smem;
    _Float16* Wbuf = (_Float16*)(smem + ABYTES);

    const int tid  = threadIdx.x;
    const int lane = tid & 63;
    const int wave = tid >> 6;
    const int wm   = wave & 1;             // wave row (0..1) -> 48 rows each
    const int wn   = wave >> 1;            // wave col (0..3) -> NT*16 cols each
    const int l15  = lane & 15;
    const int q    = lane >> 4;

    const long rowbase = (long)blockIdx.x * 96;

    float dinv[12];
    #pragma unroll
    for (int r = 0; r < 12; ++r) dinv[r] = 1.0f / sqrtf((float)kDeg[r]);

    f32x4 acc[3][NT];
    #pragma unroll
    for (int a = 0; a < 3; ++a)
        #pragma unroll
        for (int b = 0; b < NT; ++b)
            acc[a][b] = (f32x4){0.f, 0.f, 0.f, 0.f};

    for (int kc = 0; kc < K / 64; ++kc) {
        if (tid < 256) {
            // Stage + lead-mix the input tile: thread = (group g, float2-col f2).
            const int g  = tid >> 5;
            const int f2 = tid & 31;
            float2 y[12];
            #pragma unroll
            for (int n = 0; n < 12; ++n) {
                const long off = (rowbase + g*12 + n) * K + kc*64 + f2*2;
                float vx, vy;
                if (IN_F16) {
                    const _Float16* p = (const _Float16*)inp + off;
                    vx = (float)p[0]; vy = (float)p[1];
                } else {
                    const float* p = (const float*)inp + off;
                    vx = p[0]; vy = p[1];
                }
                y[n].x = dinv[n] * vx;
                y[n].y = dinv[n] * vy;
            }
            #pragma unroll
            for (int r = 0; r < 12; ++r) {
                float sx = 2.0f * y[r].x;      // self-loop weight 2
                float sy = 2.0f * y[r].y;
                #pragma unroll
                for (int j = 0; j < 12; ++j) {
                    if ((kMask[r] >> j) & 1u) { sx += y[j].x; sy += y[j].y; }
                }
                sx *= dinv[r]; sy *= dinv[r];
                f16x2 h2; h2.x = (_Float16)sx; h2.y = (_Float16)sy;
                *(f16x2*)&Abuf[(g*12 + r) * AST + f2*2] = h2;
            }
        } else {
            // Stage W^T chunk: rows o (out-feature), 64 contiguous k halves.
            const int t2   = tid - 256;
            const int k8   = t2 & 7;           // 16B chunk within the 64-k row
            const int orow = t2 >> 3;          // 0..31
            #pragma unroll
            for (int pass = 0; pass < N / 32; ++pass) {
                const int o = pass*32 + orow;
                const uint4 d = *(const uint4*)(wt + (long)o*K + kc*64 + k8*8);
                *(uint4*)&Wbuf[o*AST + k8*8] = d;
            }
        }
        __syncthreads();

        #pragma unroll
        for (int ks = 0; ks < 2; ++ks) {       // two 16x16x32 k-steps per chunk
            f16x8 af[3];
            f16x8 bf[NT];
            #pragma unroll
            for (int tm = 0; tm < 3; ++tm)
                af[tm] = *(const f16x8*)&Abuf[(wm*48 + tm*16 + l15)*AST + ks*32 + q*8];
            #pragma unroll
            for (int tn = 0; tn < NT; ++tn)
                bf[tn] = *(const f16x8*)&Wbuf[(wn*NT*16 + tn*16 + l15)*AST + ks*32 + q*8];
            #pragma unroll
            for (int tm = 0; tm < 3; ++tm)
                #pragma unroll
                for (int tn = 0; tn < NT; ++tn)
                    acc[tm][tn] = __builtin_amdgcn_mfma_f32_16x16x32_f16(
                        af[tm], bf[tn], acc[tm][tn], 0, 0, 0);
        }
        __syncthreads();
    }

    if (!POOL) {
        // Epilogue: bias + relu, store fp16 hidden activations.
        _Float16* hout = (_Float16*)outp;
        float bcol[NT];
        #pragma unroll
        for (int tn = 0; tn < NT; ++tn) bcol[tn] = bias[wn*NT*16 + tn*16 + l15];
        #pragma unroll
        for (int tm = 0; tm < 3; ++tm) {
            #pragma unroll
            for (int tn = 0; tn < NT; ++tn) {
                #pragma unroll
                for (int r = 0; r < 4; ++r) {
                    const long row = rowbase + wm*48 + tm*16 + q*4 + r;
                    const int  col = wn*NT*16 + tn*16 + l15;
                    float v = acc[tm][tn][r] + bcol[tn];
                    if (RELU) v = fmaxf(v, 0.0f);
                    hout[row*N + col] = (_Float16)v;
                }
            }
        }
    } else {
        // Epilogue: pool mean/max over the 12 leads of each batch group.
        // bias is per-column constant => apply after pooling (valid for mean and max).
        float* C = (float*)smem;               // staging buffers dead (post-barrier)
        #pragma unroll
        for (int tm = 0; tm < 3; ++tm)
            #pragma unroll
            for (int tn = 0; tn < NT; ++tn)
                #pragma unroll
                for (int r = 0; r < 4; ++r) {
                    const int row = wm*48 + tm*16 + q*4 + r;
                    const int col = wn*NT*16 + tn*16 + l15;
                    C[row*129 + col] = acc[tm][tn][r];
                }
        __syncthreads();
        float* out = (float*)outp;
        #pragma unroll
        for (int p = 0; p < 2; ++p) {
            const int idx = tid + p*512;       // 8 groups x 128 cols = 1024
            const int bl  = idx >> 7;
            const int col = idx & 127;
            float s = 0.0f, mx = -INFINITY;
            #pragma unroll
            for (int n = 0; n < 12; ++n) {
                const float v = C[(bl*12 + n)*129 + col];
                s += v; mx = fmaxf(mx, v);
            }
            const float b  = bias[col];
            const long  ob = ((long)blockIdx.x*8 + bl) * 256;
            out[ob + col]       = s / 12.0f + b;
            out[ob + 128 + col] = mx + b;
        }
    }
}

// Convert W1/W2/W3 (fp32, K x N) to fp16 transposed (N x K) in workspace.
__global__ void prep_weights(const float* __restrict__ W1,
                             const float* __restrict__ W2,
                             const float* __restrict__ W3,
                             _Float16* __restrict__ wt)
{
    const int tid = blockIdx.x * 256 + threadIdx.x;
    constexpr int N1 = 512*256, N2 = 256*256, N3 = 256*128;
    if (tid < N1) {
        const int o = tid >> 9, k = tid & 511;          // wt1: 256 x 512
        wt[tid] = (_Float16)W1[k*256 + o];
    } else if (tid < N1 + N2) {
        const int t = tid - N1;
        const int o = t >> 8, k = t & 255;              // wt2: 256 x 256
        wt[N1 + t] = (_Float16)W2[k*256 + o];
    } else if (tid < N1 + N2 + N3) {
        const int t = tid - N1 - N2;
        const int o = t >> 8, k = t & 255;              // wt3: 128 x 256
        wt[N1 + N2 + t] = (_Float16)W3[k*128 + o];      // W3 is (256,128): stride 128
    }
}

extern "C" void kernel_launch(void* const* d_in, const int* in_sizes, int n_in,
                              void* d_out, int out_size, void* d_ws, size_t ws_size,
                              hipStream_t stream)
{
    const float* x  = (const float*)d_in[0];
    const float* W1 = (const float*)d_in[1];
    const float* b1 = (const float*)d_in[2];
    const float* W2 = (const float*)d_in[3];
    const float* b2 = (const float*)d_in[4];
    const float* W3 = (const float*)d_in[5];
    const float* b3 = (const float*)d_in[6];
    float* out = (float*)d_out;

    // ws layout (halves): wt1 | wt2 | wt3 | h1 (196608x256) | h2 (196608x256)
    _Float16* wt  = (_Float16*)d_ws;
    _Float16* wt1 = wt;
    _Float16* wt2 = wt + 512*256;
    _Float16* wt3 = wt + 512*256 + 256*256;
    _Float16* h1  = wt + 512*256 + 256*256 + 256*128;
    _Float16* h2  = h1 + (long)196608 * 256;

    prep_weights<<<896, 256, 0, stream>>>(W1, W2, W3, wt);

    gcn_layer<512, 256, false, true,  false><<<2048, 512, 0, stream>>>(x,  wt1, b1, h1);
    gcn_layer<256, 256, true,  true,  false><<<2048, 512, 0, stream>>>(h1, wt2, b2, h2);
    gcn_layer<256, 128, true,  false, true ><<<2048, 512, 0, stream>>>(h2, wt3, b3, out);
}